// Round 7
// baseline (255.459 us; speedup 1.0000x reference)
//
#include <hip/hip_runtime.h>
#include <math.h>

#define B_ 8
#define T1_ 32
#define T2_ 32
#define T3_ 16
#define D_ 512
#define L_ 20
#define DL_ 128
#define M_ (B_*T1_*T2_*T3_)   // 131072

// workspace layout (float offsets)
#define WS_FW   0                      // B*L*DL
#define WS_KQ   20480                  // B*L*DL
#define WS_FS   40960                  // B*DL
#define WS_SB   41984                  // B*L
#define WS_WDB  42144                  // Wc_down bf16: 65536 ushort
#define WS_WUB  74912                  // Wc_up   bf16: 65536 ushort

typedef __attribute__((ext_vector_type(8))) short short8_t;
typedef __attribute__((ext_vector_type(4))) float f32x4;

__device__ __forceinline__ unsigned short f2b(float f) {
  unsigned int u = __float_as_uint(f);
  return (unsigned short)((u + 0x7fffu + ((u >> 16) & 1u)) >> 16);
}
__device__ __forceinline__ float b2f(short s) {
  return __uint_as_float(((unsigned)(unsigned short)s) << 16);
}
__device__ __forceinline__ int4 pack8(float4 a, float4 b) {
  int4 p;
  p.x = (int)f2b(a.x) | ((int)f2b(a.y) << 16);
  p.y = (int)f2b(a.z) | ((int)f2b(a.w) << 16);
  p.z = (int)f2b(b.x) | ((int)f2b(b.y) << 16);
  p.w = (int)f2b(b.z) | ((int)f2b(b.w) << 16);
  return p;
}

// ---------------------------------------------------------------------------
// K0: convert Wc_down [128][512] and Wc_up [512][128] fp32 -> bf16 in ws
// ---------------------------------------------------------------------------
__global__ __launch_bounds__(256) void k0_convert(
    const float* __restrict__ Wd, const float* __restrict__ Wu,
    unsigned short* __restrict__ wdb, unsigned short* __restrict__ wub) {
  int g = blockIdx.x * 256 + threadIdx.x;      // 0..32767
  if (g < 16384) {
    float4 v = ((const float4*)Wd)[g];
    ushort4 h; h.x = f2b(v.x); h.y = f2b(v.y); h.z = f2b(v.z); h.w = f2b(v.w);
    ((ushort4*)wdb)[g] = h;
  } else {
    int q = g - 16384;
    float4 v = ((const float4*)Wu)[q];
    ushort4 h; h.x = f2b(v.x); h.y = f2b(v.y); h.z = f2b(v.z); h.w = f2b(v.w);
    ((ushort4*)wub)[q] = h;
  }
}

// ---------------------------------------------------------------------------
// K1: tiny projections. grid = B*L blocks, 128 threads.
// ---------------------------------------------------------------------------
__global__ __launch_bounds__(128) void k1_small(
    const float* __restrict__ f_w, const float* __restrict__ f_s,
    const float* __restrict__ Ww, const float* __restrict__ bw,
    const float* __restrict__ Ws, const float* __restrict__ bs,
    const float* __restrict__ Wq, const float* __restrict__ bq,
    const float* __restrict__ Wk, const float* __restrict__ bk,
    float* __restrict__ ws) {
  const int bl = blockIdx.x;
  const int b = bl / L_, l = bl % L_;
  const int d = threadIdx.x;
  __shared__ float s_fw[DL_];
  __shared__ float s_k[DL_];
  {
    const float* x = f_w + (size_t)(b*L_+l)*D_;
    const float* w = Ww + (size_t)d*D_;
    float acc = 0.f;
    for (int i = 0; i < D_; i += 4)
      acc += x[i]*w[i] + x[i+1]*w[i+1] + x[i+2]*w[i+2] + x[i+3]*w[i+3];
    acc += bw[d];
    s_fw[d] = acc;
    ws[WS_FW + (b*L_+l)*DL_ + d] = acc;
  }
  if (l == 0) {
    const float* x = f_s + (size_t)b*D_;
    const float* w = Ws + (size_t)d*D_;
    float acc = 0.f;
    for (int i = 0; i < D_; i += 4)
      acc += x[i]*w[i] + x[i+1]*w[i+1] + x[i+2]*w[i+2] + x[i+3]*w[i+3];
    ws[WS_FS + b*DL_ + d] = acc + bs[d];
  }
  __syncthreads();
  {
    const float* w = Wk + (size_t)d*DL_;
    float acc = 0.f;
    for (int i = 0; i < DL_; ++i) acc += s_fw[i]*w[i];
    s_k[d] = acc + bk[d];
  }
  __syncthreads();
  {
    float acc = 0.f;
    for (int c = 0; c < DL_; ++c) acc += s_k[c] * Wq[c*DL_ + d];
    ws[WS_KQ + (b*L_+l)*DL_ + d] = acc;
  }
  if (d == 0) {
    float acc = 0.f;
    for (int c = 0; c < DL_; ++c) acc += bq[c]*s_k[c];
    ws[WS_SB + b*L_ + l] = acc;
  }
}

// ---------------------------------------------------------------------------
// K2: fused per 32-row tile. All matmul phases on MFMA; async-split staging
// (issue-early named-reg prefetch, store-late). 40 KB LDS -> 4 blocks/CU.
// ---------------------------------------------------------------------------
// LDS byte offsets
#define SFCH_B 0        // f_c_hat bf16 [32][256B], XOR-swizzled ((r&7)<<4)
#define FCQ_B  8192     // f_cq / f_cc_hat bf16 [32][256B], swizzled
#define WD_B   16384    // down: Wd chunk [128][128B] swz
#define FC_B   32768    // down: f_c chunk [32][128B] swz
#define KQ_B   16384    // mid: kq bf16 [32][256B] swz, rows>=20 zero
#define FWT_B  24576    // mid: fw^T bf16 [128][64B] swz ((d&3)<<4)
#define ATB_B  32768    // mid: attn bf16 [32][128B] swz, k>=20 zero
#define FS_B   36864    // mid: f_s_hat f32 [128]
#define SB_B   37376    // mid: sb f32 [20]
#define ATTN_B 37504    // mid: attn f32 [32][21]  (aliased by sAc later)
#define AC_B   37504    // mid: A_c f32 [32][17]   (alias: disjoint in time)
#define WU_B   16384    // up: Wu chunk [64][256B] swz
#define SMEM_B 40960

__global__ __launch_bounds__(256, 4) void k2_fused(
    const float* __restrict__ f_c, const unsigned short* __restrict__ wdb,
    const unsigned short* __restrict__ wub,
    const float* __restrict__ bc_down, const float* __restrict__ bc_up,
    const float* __restrict__ f_m, const float* __restrict__ f_s,
    const float* __restrict__ ws, float* __restrict__ out) {
  __shared__ __align__(16) char smb[SMEM_B];
  float* sAttn = (float*)(smb + ATTN_B);
  float* sAc   = (float*)(smb + AC_B);
  float* sFs   = (float*)(smb + FS_B);
  float* sSb   = (float*)(smb + SB_B);

  const int t = threadIdx.x;
  const int row0 = blockIdx.x * 32;
  const int b = row0 >> 14;
  const int lane = t & 63, w = t >> 6;
  const int l15 = lane & 15, l4 = lane >> 4;
  const int wr = (w & 1) * 16;        // activation-row group
  const int wc = w >> 1;              // d-col group
  const float inv_sqrt_dl = 0.08838834764831843f;
  const f32x4 z4 = {0.f, 0.f, 0.f, 0.f};

  // ---------------- down GEMM: async-split staging pipeline ----------------
  const int wd_d = t >> 3;            // 0..31 (staging row base)
  const int wd_k = (t & 7) * 8;       // k-element offset within chunk
  const int wd_swz = (wd_k * 2) ^ ((wd_d & 7) << 4);   // same for rows +32i
  int4 wA, wB, wC, wD;
  float4 fv0, fv1;

  // prologue: issue chunk-0 loads
  {
    const unsigned short* wp = wdb + wd_k;
    wA = *(const int4*)(wp + (size_t)(wd_d      )*D_);
    wB = *(const int4*)(wp + (size_t)(wd_d + 32 )*D_);
    wC = *(const int4*)(wp + (size_t)(wd_d + 64 )*D_);
    wD = *(const int4*)(wp + (size_t)(wd_d + 96 )*D_);
    const float* src = f_c + (size_t)(row0 + wd_d)*D_ + wd_k;
    fv0 = *(const float4*)src; fv1 = *(const float4*)(src + 4);
  }

  f32x4 dacc[4];
  #pragma unroll
  for (int cf = 0; cf < 4; ++cf) dacc[cf] = z4;

  for (int kc = 0; kc < D_; kc += 64) {
    // store-late: staged regs -> LDS (compiler inserts vmcnt wait here)
    *(int4*)(smb + WD_B + (wd_d     )*128 + wd_swz) = wA;
    *(int4*)(smb + WD_B + (wd_d + 32)*128 + wd_swz) = wB;
    *(int4*)(smb + WD_B + (wd_d + 64)*128 + wd_swz) = wC;
    *(int4*)(smb + WD_B + (wd_d + 96)*128 + wd_swz) = wD;
    *(int4*)(smb + FC_B + wd_d*128 + wd_swz) = pack8(fv0, fv1);
    __syncthreads();
    // issue-early: next chunk's loads, in flight across the MFMAs
    if (kc + 64 < D_) {
      const int kn = kc + 64;
      const unsigned short* wp = wdb + kn + wd_k;
      wA = *(const int4*)(wp + (size_t)(wd_d      )*D_);
      wB = *(const int4*)(wp + (size_t)(wd_d + 32 )*D_);
      wC = *(const int4*)(wp + (size_t)(wd_d + 64 )*D_);
      wD = *(const int4*)(wp + (size_t)(wd_d + 96 )*D_);
      const float* src = f_c + (size_t)(row0 + wd_d)*D_ + kn + wd_k;
      fv0 = *(const float4*)src; fv1 = *(const float4*)(src + 4);
    }
    #pragma unroll
    for (int ks = 0; ks < 2; ++ks) {
      const int rr = wr + l15;
      short8_t bfrag = *(const short8_t*)(smb + FC_B + rr*128 +
                        ((ks*64 + l4*16) ^ ((rr & 7) << 4)));
      #pragma unroll
      for (int cf = 0; cf < 4; ++cf) {
        const int d = wc*64 + cf*16 + l15;
        short8_t afrag = *(const short8_t*)(smb + WD_B + d*128 +
                          ((ks*64 + l4*16) ^ ((d & 7) << 4)));
        dacc[cf] = __builtin_amdgcn_mfma_f32_16x16x32_bf16(afrag, bfrag, dacc[cf], 0, 0, 0);
      }
    }
    __syncthreads();
  }
  // writeout f_c_hat (bf16, swizzled): lane holds row rr, 4 consecutive d
  {
    const int rr = wr + l15;
    const int rs = (rr & 7) << 4;
    #pragma unroll
    for (int cf = 0; cf < 4; ++cf) {
      const int d0 = wc*64 + cf*16 + l4*4;
      float4 bias = *(const float4*)(bc_down + d0);
      ushort4 pk;
      pk.x = f2b(dacc[cf][0] + bias.x); pk.y = f2b(dacc[cf][1] + bias.y);
      pk.z = f2b(dacc[cf][2] + bias.z); pk.w = f2b(dacc[cf][3] + bias.w);
      *(ushort4*)(smb + SFCH_B + rr*256 + ((d0*2) ^ rs)) = pk;
    }
  }
  // stage kq [32][256B] swz (rows >= 20 zero)
  for (int p = t; p < 32*16; p += 256) {
    const int l = p >> 4, k8 = (p & 15) * 8;
    int4 v = {0,0,0,0};
    if (l < L_) {
      float4 a0 = *(const float4*)(ws + WS_KQ + (b*L_+l)*DL_ + k8);
      float4 a1 = *(const float4*)(ws + WS_KQ + (b*L_+l)*DL_ + k8 + 4);
      v = pack8(a0, a1);
    }
    *(int4*)(smb + KQ_B + l*256 + ((k8*2) ^ ((l & 7) << 4))) = v;
  }
  // stage fw^T [128 d][64B] swz: fwT[d][l] = fw[l][d], l >= 20 zero
  for (int p = t; p < 512; p += 256) {
    const int d = p >> 2, l8 = (p & 3) * 8;
    float vv[8];
    #pragma unroll
    for (int e = 0; e < 8; ++e) {
      const int l = l8 + e;
      vv[e] = (l < L_) ? ws[WS_FW + (b*L_+l)*DL_ + d] : 0.f;
    }
    int4 v;
    v.x = (int)f2b(vv[0]) | ((int)f2b(vv[1]) << 16);
    v.y = (int)f2b(vv[2]) | ((int)f2b(vv[3]) << 16);
    v.z = (int)f2b(vv[4]) | ((int)f2b(vv[5]) << 16);
    v.w = (int)f2b(vv[6]) | ((int)f2b(vv[7]) << 16);
    *(int4*)(smb + FWT_B + d*64 + ((l8*2) ^ ((d & 3) << 4))) = v;
  }
  if (t < 32) *(float4*)(sFs + t*4) = *(const float4*)(ws + WS_FS + b*DL_ + t*4);
  if (t < L_) sSb[t] = ws[WS_SB + b*L_ + t];
  __syncthreads();

  // ---------------- phase2: scores via MFMA --------------------------------
  {
    const int lt = w & 1, rt = w >> 1;
    const int arow = lt*16 + l15;       // kq row (l index)
    const int brow = rt*16 + l15;       // f_c_hat row (r index)
    f32x4 sacc = z4;
    #pragma unroll
    for (int ks = 0; ks < 4; ++ks) {
      short8_t af = *(const short8_t*)(smb + KQ_B + arow*256 +
                     ((ks*64 + l4*16) ^ ((arow & 7) << 4)));
      short8_t bf = *(const short8_t*)(smb + SFCH_B + brow*256 +
                     ((ks*64 + l4*16) ^ ((brow & 7) << 4)));
      sacc = __builtin_amdgcn_mfma_f32_16x16x32_bf16(af, bf, sacc, 0, 0, 0);
    }
    const int r2 = rt*16 + l15;
    #pragma unroll
    for (int reg = 0; reg < 4; ++reg) {
      const int lval = lt*16 + l4*4 + reg;
      if (lval < L_) sAttn[r2*21 + lval] = (sacc[reg] + sSb[lval]) * inv_sqrt_dl;
    }
  }
  __syncthreads();
  if (t < 32) {                          // softmax over L (20-wide, cheap)
    float* srow = sAttn + t*21;
    float m = -1e30f;
    for (int l = 0; l < L_; ++l) m = fmaxf(m, srow[l]);
    float sum = 0.f;
    for (int l = 0; l < L_; ++l) { float e = __expf(srow[l]-m); srow[l] = e; sum += e; }
    float inv = 1.f/sum;
    for (int l = 0; l < L_; ++l) srow[l] *= inv;
  }
  __syncthreads();
  // pack attn -> bf16 B-operand [32][128B] swz (k >= 20 zero)
  {
    const int r = t >> 3, k8 = (t & 7) * 8;
    int4 v = {0,0,0,0};
    if (k8 < L_) {
      float vv[8];
      #pragma unroll
      for (int e = 0; e < 8; ++e) {
        const int l = k8 + e;
        vv[e] = (l < L_) ? sAttn[r*21 + l] : 0.f;
      }
      v.x = (int)f2b(vv[0]) | ((int)f2b(vv[1]) << 16);
      v.y = (int)f2b(vv[2]) | ((int)f2b(vv[3]) << 16);
      v.z = (int)f2b(vv[4]) | ((int)f2b(vv[5]) << 16);
      v.w = (int)f2b(vv[6]) | ((int)f2b(vv[7]) << 16);
    }
    *(int4*)(smb + ATB_B + r*128 + ((k8*2) ^ ((r & 7) << 4))) = v;
  }
  __syncthreads();
  // ---------------- phase3: f_caq via MFMA, gate, -> FCQ bf16 --------------
  {
    f32x4 cacc[2][2];
    cacc[0][0] = z4; cacc[0][1] = z4; cacc[1][0] = z4; cacc[1][1] = z4;
    #pragma unroll
    for (int dt = 0; dt < 2; ++dt) {
      const int arow = (w*2 + dt)*16 + l15;   // fwT row (d index)
      short8_t af = *(const short8_t*)(smb + FWT_B + arow*64 +
                     ((l4*16) ^ ((arow & 3) << 4)));
      #pragma unroll
      for (int rt = 0; rt < 2; ++rt) {
        const int brow = rt*16 + l15;          // attn row (r index)
        short8_t bf = *(const short8_t*)(smb + ATB_B + brow*128 +
                       ((l4*16) ^ ((brow & 7) << 4)));
        cacc[dt][rt] = __builtin_amdgcn_mfma_f32_16x16x32_bf16(af, bf, cacc[dt][rt], 0, 0, 0);
      }
    }
    #pragma unroll
    for (int dt = 0; dt < 2; ++dt)
    #pragma unroll
    for (int rt = 0; rt < 2; ++rt) {
      const int d0 = (w*2 + dt)*16 + l4*4;
      const int r = rt*16 + l15;
      const int rs = (r & 7) << 4;
      float4 fs4 = *(const float4*)(sFs + d0);
      ushort4 fh = *(const ushort4*)(smb + SFCH_B + r*256 + ((d0*2) ^ rs));
      ushort4 pk;
      pk.x = f2b(b2f((short)fh.x)*(cacc[dt][rt][0] + fs4.x));
      pk.y = f2b(b2f((short)fh.y)*(cacc[dt][rt][1] + fs4.y));
      pk.z = f2b(b2f((short)fh.z)*(cacc[dt][rt][2] + fs4.z));
      pk.w = f2b(b2f((short)fh.w)*(cacc[dt][rt][3] + fs4.w));
      *(ushort4*)(smb + FCQ_B + r*256 + ((d0*2) ^ rs)) = pk;
    }
  }
  __syncthreads();
  // ---------------- phase4: A_c via Gram MFMA + wave-parallel softmax ------
  if (w < 2) {
    const int zrow = w*16 + l15;
    f32x4 pacc = z4;
    #pragma unroll
    for (int ks = 0; ks < 4; ++ks) {
      short8_t fq = *(const short8_t*)(smb + FCQ_B + zrow*256 +
                     ((ks*64 + l4*16) ^ ((zrow & 7) << 4)));
      pacc = __builtin_amdgcn_mfma_f32_16x16x32_bf16(fq, fq, pacc, 0, 0, 0);
    }
    float p0[4], m[4], e[4], s[4];
    #pragma unroll
    for (int reg = 0; reg < 4; ++reg) p0[reg] = pacc[reg] * inv_sqrt_dl;
    #pragma unroll
    for (int reg = 0; reg < 4; ++reg) {
      m[reg] = p0[reg];
      m[reg] = fmaxf(m[reg], __shfl_xor(m[reg], 1));
      m[reg] = fmaxf(m[reg], __shfl_xor(m[reg], 2));
      m[reg] = fmaxf(m[reg], __shfl_xor(m[reg], 4));
      m[reg] = fmaxf(m[reg], __shfl_xor(m[reg], 8));
      e[reg] = __expf(p0[reg] - m[reg]);
      s[reg] = e[reg];
      s[reg] += __shfl_xor(s[reg], 1);
      s[reg] += __shfl_xor(s[reg], 2);
      s[reg] += __shfl_xor(s[reg], 4);
      s[reg] += __shfl_xor(s[reg], 8);
    }
    #pragma unroll
    for (int reg = 0; reg < 4; ++reg)
      sAc[(w*16 + l4*4 + reg)*17 + l15] = e[reg] / s[reg];
  }
  __syncthreads();

  // ---------------- up GEMM prologue: issue Wu ch0 while phase5 runs -------
  const int wu_d = t >> 4;            // 0..15 (staging row base)
  const int wu_k = (t & 15) * 8;      // k-element offset
  const int wu_swz = (wu_k * 2) ^ ((wu_d & 7) << 4);  // rows +16i: (d&7) flips by 16? no: +16 ≡ 0 mod 8 -> same
  int4 u0, u1, u2, u3;
  {
    const unsigned short* up = wub + wu_k;
    u0 = *(const int4*)(up + (size_t)(wu_d     )*DL_);
    u1 = *(const int4*)(up + (size_t)(wu_d + 16)*DL_);
    u2 = *(const int4*)(up + (size_t)(wu_d + 32)*DL_);
    u3 = *(const int4*)(up + (size_t)(wu_d + 48)*DL_);
  }
  // ---------------- phase5: f_cc_hat -> bf16 swizzled (over FCQ) -----------
  for (int p = t; p < 1024; p += 256) {
    const int r = p >> 5, d4 = (p & 31)*4;
    const int g = r >> 4, z = r & 15;
    float ax = 0.f, ay = 0.f, az = 0.f, aw = 0.f;
    #pragma unroll
    for (int wq = 0; wq < 16; ++wq) {
      float a = sAc[(g*16+z)*17 + wq];
      const int fr = g*16 + wq;
      ushort4 fv = *(const ushort4*)(smb + SFCH_B + fr*256 + ((d4*2) ^ ((fr & 7) << 4)));
      ax += a*b2f((short)fv.x); ay += a*b2f((short)fv.y);
      az += a*b2f((short)fv.z); aw += a*b2f((short)fv.w);
    }
    ushort4 pk;
    pk.x = f2b(ax); pk.y = f2b(ay); pk.z = f2b(az); pk.w = f2b(aw);
    *(ushort4*)(smb + FCQ_B + r*256 + ((d4*2) ^ ((r & 7) << 4))) = pk;
  }
  // store-late Wu ch0 (WU region is dead mid-phase space; safe since phase4 barrier)
  *(int4*)(smb + WU_B + (wu_d     )*256 + wu_swz) = u0;
  *(int4*)(smb + WU_B + (wu_d + 16)*256 + wu_swz) = u1;
  *(int4*)(smb + WU_B + (wu_d + 32)*256 + wu_swz) = u2;
  *(int4*)(smb + WU_B + (wu_d + 48)*256 + wu_swz) = u3;
  __syncthreads();

  // ---------------- up GEMM + epilogue, pipelined --------------------------
  const int rr = wr + l15;
  const char* fcqrow = smb + FCQ_B + rr*256;
  const int xsw = (rr & 7) << 4;
  const int grow = row0 + rr;
  const size_t obase = (size_t)grow * D_;
  const size_t mbase = (size_t)(grow >> 4) * D_;
  for (int ch = 0; ch < 8; ++ch) {
    // issue-early: next Wu chunk (regs already stored to LDS)
    if (ch < 7) {
      const unsigned short* up = wub + (size_t)(ch + 1)*64*DL_ + wu_k;
      u0 = *(const int4*)(up + (size_t)(wu_d     )*DL_);
      u1 = *(const int4*)(up + (size_t)(wu_d + 16)*DL_);
      u2 = *(const int4*)(up + (size_t)(wu_d + 32)*DL_);
      u3 = *(const int4*)(up + (size_t)(wu_d + 48)*DL_);
    }
    f32x4 uacc[2]; uacc[0] = z4; uacc[1] = z4;
    #pragma unroll
    for (int ks = 0; ks < 4; ++ks) {
      short8_t bfrag = *(const short8_t*)(fcqrow + ((ks*64 + l4*16) ^ xsw));
      #pragma unroll
      for (int cf = 0; cf < 2; ++cf) {
        const int dd = wc*32 + cf*16 + l15;
        short8_t afrag = *(const short8_t*)(smb + WU_B + dd*256 +
                          ((ks*64 + l4*16) ^ ((dd & 7) << 4)));
        uacc[cf] = __builtin_amdgcn_mfma_f32_16x16x32_bf16(afrag, bfrag, uacc[cf], 0, 0, 0);
      }
    }
    #pragma unroll
    for (int cf = 0; cf < 2; ++cf) {
      const int d0 = ch*64 + wc*32 + cf*16 + l4*4;
      float4 bias = *(const float4*)(bc_up + d0);
      float4 fs4 = *(const float4*)(f_s + (size_t)b*D_ + d0);
      float4 fm4 = *(const float4*)(f_m + mbase + d0);
      float4 fc4 = *(const float4*)(f_c + obase + d0);
      float4 o;
      o.x = uacc[cf][0] + bias.x + fc4.x + fm4.x/(1.f + __expf(-fm4.x*fs4.x));
      o.y = uacc[cf][1] + bias.y + fc4.y + fm4.y/(1.f + __expf(-fm4.y*fs4.y));
      o.z = uacc[cf][2] + bias.z + fc4.z + fm4.z/(1.f + __expf(-fm4.z*fs4.z));
      o.w = uacc[cf][3] + bias.w + fc4.w + fm4.w/(1.f + __expf(-fm4.w*fs4.w));
      *(float4*)(out + obase + d0) = o;
    }
    if (ch < 7) {
      __syncthreads();              // all waves done reading WU[ch]
      *(int4*)(smb + WU_B + (wu_d     )*256 + wu_swz) = u0;
      *(int4*)(smb + WU_B + (wu_d + 16)*256 + wu_swz) = u1;
      *(int4*)(smb + WU_B + (wu_d + 32)*256 + wu_swz) = u2;
      *(int4*)(smb + WU_B + (wu_d + 48)*256 + wu_swz) = u3;
      __syncthreads();
    }
  }
}

extern "C" void kernel_launch(void* const* d_in, const int* in_sizes, int n_in,
                              void* d_out, int out_size, void* d_ws, size_t ws_size,
                              hipStream_t stream) {
  (void)in_sizes; (void)n_in; (void)out_size; (void)ws_size;
  const float* f_c     = (const float*)d_in[0];
  const float* f_w     = (const float*)d_in[1];
  const float* f_s     = (const float*)d_in[2];
  const float* f_m     = (const float*)d_in[3];
  const float* Wc_down = (const float*)d_in[4];
  const float* bc_down = (const float*)d_in[5];
  const float* Ww      = (const float*)d_in[6];
  const float* bw      = (const float*)d_in[7];
  const float* Ws      = (const float*)d_in[8];
  const float* bs      = (const float*)d_in[9];
  const float* Wq      = (const float*)d_in[10];
  const float* bq      = (const float*)d_in[11];
  const float* Wk      = (const float*)d_in[12];
  const float* bk      = (const float*)d_in[13];
  const float* Wc_up   = (const float*)d_in[14];
  const float* bc_up   = (const float*)d_in[15];
  float* out = (float*)d_out;
  float* wsf = (float*)d_ws;
  unsigned short* wdb = (unsigned short*)(wsf + WS_WDB);
  unsigned short* wub = (unsigned short*)(wsf + WS_WUB);

  hipLaunchKernelGGL(k0_convert, dim3(128), dim3(256), 0, stream,
                     Wc_down, Wc_up, wdb, wub);
  hipLaunchKernelGGL(k1_small, dim3(B_*L_), dim3(128), 0, stream,
                     f_w, f_s, Ww, bw, Ws, bs, Wq, bq, Wk, bk, wsf);
  hipLaunchKernelGGL(k2_fused, dim3(M_/32), dim3(256), 0, stream,
                     f_c, wdb, wub, bc_down, bc_up, f_m, f_s, wsf, out);
}

// Round 8
// 245.175 us; speedup vs baseline: 1.0419x; 1.0419x over previous
//
#include <hip/hip_runtime.h>
#include <math.h>

#define B_ 8
#define T1_ 32
#define T2_ 32
#define T3_ 16
#define D_ 512
#define L_ 20
#define DL_ 128
#define M_ (B_*T1_*T2_*T3_)   // 131072
#define ROWS 64               // rows per block

// workspace layout (float offsets)
#define WS_FW   0                      // B*L*DL
#define WS_KQ   20480                  // B*L*DL
#define WS_FS   40960                  // B*DL
#define WS_SB   41984                  // B*L
#define WS_WDB  42144                  // Wc_down bf16: 65536 ushort
#define WS_WUB  74912                  // Wc_up   bf16: 65536 ushort

typedef __attribute__((ext_vector_type(8))) short short8_t;
typedef __attribute__((ext_vector_type(4))) float f32x4;

__device__ __forceinline__ unsigned short f2b(float f) {
  unsigned int u = __float_as_uint(f);
  return (unsigned short)((u + 0x7fffu + ((u >> 16) & 1u)) >> 16);
}
__device__ __forceinline__ float b2f(short s) {
  return __uint_as_float(((unsigned)(unsigned short)s) << 16);
}
__device__ __forceinline__ int4 pack8(float4 a, float4 b) {
  int4 p;
  p.x = (int)f2b(a.x) | ((int)f2b(a.y) << 16);
  p.y = (int)f2b(a.z) | ((int)f2b(a.w) << 16);
  p.z = (int)f2b(b.x) | ((int)f2b(b.y) << 16);
  p.w = (int)f2b(b.z) | ((int)f2b(b.w) << 16);
  return p;
}

// ---------------------------------------------------------------------------
// K0: convert Wc_down [128][512] and Wc_up [512][128] fp32 -> bf16 in ws
// ---------------------------------------------------------------------------
__global__ __launch_bounds__(256) void k0_convert(
    const float* __restrict__ Wd, const float* __restrict__ Wu,
    unsigned short* __restrict__ wdb, unsigned short* __restrict__ wub) {
  int g = blockIdx.x * 256 + threadIdx.x;      // 0..32767
  if (g < 16384) {
    float4 v = ((const float4*)Wd)[g];
    ushort4 h; h.x = f2b(v.x); h.y = f2b(v.y); h.z = f2b(v.z); h.w = f2b(v.w);
    ((ushort4*)wdb)[g] = h;
  } else {
    int q = g - 16384;
    float4 v = ((const float4*)Wu)[q];
    ushort4 h; h.x = f2b(v.x); h.y = f2b(v.y); h.z = f2b(v.z); h.w = f2b(v.w);
    ((ushort4*)wub)[q] = h;
  }
}

// ---------------------------------------------------------------------------
// K1: tiny projections. grid = B*L blocks, 128 threads.
// ---------------------------------------------------------------------------
__global__ __launch_bounds__(128) void k1_small(
    const float* __restrict__ f_w, const float* __restrict__ f_s,
    const float* __restrict__ Ww, const float* __restrict__ bw,
    const float* __restrict__ Ws, const float* __restrict__ bs,
    const float* __restrict__ Wq, const float* __restrict__ bq,
    const float* __restrict__ Wk, const float* __restrict__ bk,
    float* __restrict__ ws) {
  const int bl = blockIdx.x;
  const int b = bl / L_, l = bl % L_;
  const int d = threadIdx.x;
  __shared__ float s_fw[DL_];
  __shared__ float s_k[DL_];
  {
    const float* x = f_w + (size_t)(b*L_+l)*D_;
    const float* w = Ww + (size_t)d*D_;
    float acc = 0.f;
    for (int i = 0; i < D_; i += 4)
      acc += x[i]*w[i] + x[i+1]*w[i+1] + x[i+2]*w[i+2] + x[i+3]*w[i+3];
    acc += bw[d];
    s_fw[d] = acc;
    ws[WS_FW + (b*L_+l)*DL_ + d] = acc;
  }
  if (l == 0) {
    const float* x = f_s + (size_t)b*D_;
    const float* w = Ws + (size_t)d*D_;
    float acc = 0.f;
    for (int i = 0; i < D_; i += 4)
      acc += x[i]*w[i] + x[i+1]*w[i+1] + x[i+2]*w[i+2] + x[i+3]*w[i+3];
    ws[WS_FS + b*DL_ + d] = acc + bs[d];
  }
  __syncthreads();
  {
    const float* w = Wk + (size_t)d*DL_;
    float acc = 0.f;
    for (int i = 0; i < DL_; ++i) acc += s_fw[i]*w[i];
    s_k[d] = acc + bk[d];
  }
  __syncthreads();
  {
    float acc = 0.f;
    for (int c = 0; c < DL_; ++c) acc += s_k[c] * Wq[c*DL_ + d];
    ws[WS_KQ + (b*L_+l)*DL_ + d] = acc;
  }
  if (d == 0) {
    float acc = 0.f;
    for (int c = 0; c < DL_; ++c) acc += bq[c]*s_k[c];
    ws[WS_SB + b*L_ + l] = acc;
  }
}

// ---------------------------------------------------------------------------
// K2: fused per 64-row tile, 512 threads (8 waves), double-buffered staging.
// LDS 80 KB -> 2 blocks/CU (16 waves/CU).
// ---------------------------------------------------------------------------
// LDS byte offsets
#define SFCH_B 0        // f_c_hat bf16 [64][256B] swz ((r&7)<<4)
#define FCQ_B  16384    // f_cq / f_cc_hat bf16 [64][256B] swz
// staging region 32768..81920, time-aliased:
#define WD0_B  32768    // down: Wd chunk [128][128B] buf0
#define WD1_B  49152    //                            buf1
#define FC0_B  65536    // down: f_c chunk [64][128B] buf0
#define FC1_B  73728    //                            buf1
#define KQ_B   32768    // mid: kq bf16 [32][256B] swz (rows>=20 zero)
#define FWT_B  40960    // mid: fw^T bf16 [128][64B] swz ((d&3)<<4)
#define ATB_B  49152    // mid: attn bf16 [64][128B] swz (slots>=20 zero)
#define ATTN_B 57344    // mid: attn f32 [64][21] = 5376B
#define WU0_B  32768    // up: Wu chunk [64][256B] buf0
#define WU1_B  49152    //                          buf1
#define SB_B   76960    // sb f32 [20]
#define FS_B   77056    // f_s_hat f32 [128]
#define AC_B   77568    // A_c f32 [64][17] = 4352B -> ends 81920
#define SMEM_B 81920

__global__ __launch_bounds__(512, 4) void k2_fused(
    const float* __restrict__ f_c, const unsigned short* __restrict__ wdb,
    const unsigned short* __restrict__ wub,
    const float* __restrict__ bc_down, const float* __restrict__ bc_up,
    const float* __restrict__ f_m, const float* __restrict__ f_s,
    const float* __restrict__ ws, float* __restrict__ out) {
  __shared__ __align__(16) char smb[SMEM_B];
  float* sAttn = (float*)(smb + ATTN_B);
  float* sAc   = (float*)(smb + AC_B);
  float* sFs   = (float*)(smb + FS_B);
  float* sSb   = (float*)(smb + SB_B);

  const int t = threadIdx.x;            // 0..511
  const int row0 = blockIdx.x * ROWS;
  const int b = row0 >> 14;
  const int lane = t & 63, w = t >> 6;  // 8 waves
  const int l15 = lane & 15, l4 = lane >> 4;
  const float inv_sqrt_dl = 0.08838834764831843f;
  const f32x4 z4 = {0.f, 0.f, 0.f, 0.f};

  // staging coords (down): 1024 int4 WD / 512 thr = 2 rows each; FC 512 int4
  const int sd_r  = t >> 3;             // 0..63
  const int sd_k8 = (t & 7) * 8;        // k element offset
  const int sd_swz = (sd_k8 * 2) ^ ((sd_r & 7) << 4);  // same for row +64

  // ---------------- down GEMM: double-buffered, 1 barrier/chunk ------------
  // wave w owns d-tile w (16 d), all 4 r-tiles
  f32x4 dacc[4];
  #pragma unroll
  for (int rt = 0; rt < 4; ++rt) dacc[rt] = z4;

  { // prologue: stage chunk 0 into buf0
    const unsigned short* wp = wdb + sd_k8;
    int4 wrA = *(const int4*)(wp + (size_t)sd_r * D_);
    int4 wrB = *(const int4*)(wp + (size_t)(sd_r + 64) * D_);
    const float* src = f_c + (size_t)(row0 + sd_r) * D_ + sd_k8;
    float4 v0 = *(const float4*)src;
    float4 v1 = *(const float4*)(src + 4);
    *(int4*)(smb + WD0_B + sd_r * 128 + sd_swz) = wrA;
    *(int4*)(smb + WD0_B + (sd_r + 64) * 128 + sd_swz) = wrB;
    *(int4*)(smb + FC0_B + sd_r * 128 + sd_swz) = pack8(v0, v1);
  }
  __syncthreads();

  {
    char* cur_wd = smb + WD0_B; char* nxt_wd = smb + WD1_B;
    char* cur_fc = smb + FC0_B; char* nxt_fc = smb + FC1_B;
    const int ad = w * 16 + l15;                 // A row (d) for this wave
    const int aswz = (ad & 7) << 4;
    for (int ch = 0; ch < 8; ++ch) {
      int4 wrA, wrB; float4 v0, v1;
      if (ch < 7) {                              // issue next chunk's loads
        const int kn = (ch + 1) * 64;
        const unsigned short* wp = wdb + kn + sd_k8;
        wrA = *(const int4*)(wp + (size_t)sd_r * D_);
        wrB = *(const int4*)(wp + (size_t)(sd_r + 64) * D_);
        const float* src = f_c + (size_t)(row0 + sd_r) * D_ + kn + sd_k8;
        v0 = *(const float4*)src; v1 = *(const float4*)(src + 4);
      }
      #pragma unroll
      for (int ks = 0; ks < 2; ++ks) {
        short8_t afrag = *(const short8_t*)(cur_wd + ad * 128 +
                          ((ks*64 + l4*16) ^ aswz));
        #pragma unroll
        for (int rt = 0; rt < 4; ++rt) {
          const int rr = rt*16 + l15;
          short8_t bfrag = *(const short8_t*)(cur_fc + rr * 128 +
                            ((ks*64 + l4*16) ^ ((rr & 7) << 4)));
          dacc[rt] = __builtin_amdgcn_mfma_f32_16x16x32_bf16(afrag, bfrag, dacc[rt], 0, 0, 0);
        }
      }
      if (ch < 7) {                              // store-late into other buf
        *(int4*)(nxt_wd + sd_r * 128 + sd_swz) = wrA;
        *(int4*)(nxt_wd + (sd_r + 64) * 128 + sd_swz) = wrB;
        *(int4*)(nxt_fc + sd_r * 128 + sd_swz) = pack8(v0, v1);
      }
      __syncthreads();
      char* tw = cur_wd; cur_wd = nxt_wd; nxt_wd = tw;
      char* tf = cur_fc; cur_fc = nxt_fc; nxt_fc = tf;
    }
  }
  // writeout f_c_hat bf16 swz: lane holds d0..d0+3 (m), row rr (n)
  {
    const int d0 = w*16 + l4*4;
    float4 bias = *(const float4*)(bc_down + d0);
    #pragma unroll
    for (int rt = 0; rt < 4; ++rt) {
      const int rr = rt*16 + l15;
      ushort4 pk;
      pk.x = f2b(dacc[rt][0] + bias.x); pk.y = f2b(dacc[rt][1] + bias.y);
      pk.z = f2b(dacc[rt][2] + bias.z); pk.w = f2b(dacc[rt][3] + bias.w);
      *(ushort4*)(smb + SFCH_B + rr*256 + ((d0*2) ^ ((rr & 7) << 4))) = pk;
    }
  }
  // stage mid smalls (single pass each, 512 threads)
  { // kq [32][256B] swz, rows >= 20 zero
    const int l = t >> 4, k8 = (t & 15) * 8;
    int4 v = {0,0,0,0};
    if (l < L_) {
      float4 a0 = *(const float4*)(ws + WS_KQ + (b*L_+l)*DL_ + k8);
      float4 a1 = *(const float4*)(ws + WS_KQ + (b*L_+l)*DL_ + k8 + 4);
      v = pack8(a0, a1);
    }
    *(int4*)(smb + KQ_B + l*256 + ((k8*2) ^ ((l & 7) << 4))) = v;
  }
  { // fw^T [128][64B] swz
    const int d = t >> 2, l8 = (t & 3) * 8;
    float vv[8];
    #pragma unroll
    for (int e = 0; e < 8; ++e) {
      const int l = l8 + e;
      vv[e] = (l < L_) ? ws[WS_FW + (b*L_+l)*DL_ + d] : 0.f;
    }
    int4 v;
    v.x = (int)f2b(vv[0]) | ((int)f2b(vv[1]) << 16);
    v.y = (int)f2b(vv[2]) | ((int)f2b(vv[3]) << 16);
    v.z = (int)f2b(vv[4]) | ((int)f2b(vv[5]) << 16);
    v.w = (int)f2b(vv[6]) | ((int)f2b(vv[7]) << 16);
    *(int4*)(smb + FWT_B + d*64 + ((l8*2) ^ ((d & 3) << 4))) = v;
  }
  if (t < 32) *(float4*)(sFs + t*4) = *(const float4*)(ws + WS_FS + b*DL_ + t*4);
  if (t < L_) sSb[t] = ws[WS_SB + b*L_ + t];
  __syncthreads();

  // ---------------- phase2: scores via MFMA (8 tiles / 8 waves) ------------
  {
    const int lt = w & 1, rt2 = w >> 1;       // l-tile, r-tile(0..3)
    const int arow = lt*16 + l15;
    const int brow = rt2*16 + l15;
    f32x4 sacc = z4;
    #pragma unroll
    for (int ks = 0; ks < 4; ++ks) {
      short8_t af = *(const short8_t*)(smb + KQ_B + arow*256 +
                     ((ks*64 + l4*16) ^ ((arow & 7) << 4)));
      short8_t bf = *(const short8_t*)(smb + SFCH_B + brow*256 +
                     ((ks*64 + l4*16) ^ ((brow & 7) << 4)));
      sacc = __builtin_amdgcn_mfma_f32_16x16x32_bf16(af, bf, sacc, 0, 0, 0);
    }
    const int r2 = rt2*16 + l15;
    #pragma unroll
    for (int reg = 0; reg < 4; ++reg) {
      const int lval = lt*16 + l4*4 + reg;
      if (lval < L_) sAttn[r2*21 + lval] = (sacc[reg] + sSb[lval]) * inv_sqrt_dl;
    }
  }
  __syncthreads();
  if (t < ROWS) {                              // softmax over L
    float* srow = sAttn + t*21;
    float m = -1e30f;
    for (int l = 0; l < L_; ++l) m = fmaxf(m, srow[l]);
    float sum = 0.f;
    for (int l = 0; l < L_; ++l) { float e = __expf(srow[l]-m); srow[l] = e; sum += e; }
    float inv = 1.f/sum;
    for (int l = 0; l < L_; ++l) srow[l] *= inv;
  }
  __syncthreads();
  { // pack attn -> bf16 [64][128B] swz
    const int r = t >> 3, k8 = (t & 7) * 8;
    int4 v = {0,0,0,0};
    if (k8 < L_) {
      float vv[8];
      #pragma unroll
      for (int e = 0; e < 8; ++e) {
        const int l = k8 + e;
        vv[e] = (l < L_) ? sAttn[r*21 + l] : 0.f;
      }
      v.x = (int)f2b(vv[0]) | ((int)f2b(vv[1]) << 16);
      v.y = (int)f2b(vv[2]) | ((int)f2b(vv[3]) << 16);
      v.z = (int)f2b(vv[4]) | ((int)f2b(vv[5]) << 16);
      v.w = (int)f2b(vv[6]) | ((int)f2b(vv[7]) << 16);
    }
    *(int4*)(smb + ATB_B + r*128 + ((k8*2) ^ ((r & 7) << 4))) = v;
  }
  __syncthreads();
  // ---------------- phase3: f_caq via MFMA (32 tiles / 8 waves) ------------
  {
    f32x4 cacc[4];
    #pragma unroll
    for (int rt = 0; rt < 4; ++rt) cacc[rt] = z4;
    const int arow = w*16 + l15;               // fwT row (d)
    short8_t af = *(const short8_t*)(smb + FWT_B + arow*64 +
                   ((l4*16) ^ ((arow & 3) << 4)));
    #pragma unroll
    for (int rt = 0; rt < 4; ++rt) {
      const int brow = rt*16 + l15;
      short8_t bf = *(const short8_t*)(smb + ATB_B + brow*128 +
                     ((l4*16) ^ ((brow & 7) << 4)));
      cacc[rt] = __builtin_amdgcn_mfma_f32_16x16x32_bf16(af, bf, cacc[rt], 0, 0, 0);
    }
    const int d0 = w*16 + l4*4;
    float4 fs4 = *(const float4*)(sFs + d0);
    #pragma unroll
    for (int rt = 0; rt < 4; ++rt) {
      const int r = rt*16 + l15;
      const int rs = (r & 7) << 4;
      ushort4 fh = *(const ushort4*)(smb + SFCH_B + r*256 + ((d0*2) ^ rs));
      ushort4 pk;
      pk.x = f2b(b2f((short)fh.x)*(cacc[rt][0] + fs4.x));
      pk.y = f2b(b2f((short)fh.y)*(cacc[rt][1] + fs4.y));
      pk.z = f2b(b2f((short)fh.z)*(cacc[rt][2] + fs4.z));
      pk.w = f2b(b2f((short)fh.w)*(cacc[rt][3] + fs4.w));
      *(ushort4*)(smb + FCQ_B + r*256 + ((d0*2) ^ rs)) = pk;
    }
  }
  __syncthreads();
  // ---------------- phase4: A_c Gram MFMA + wave-parallel softmax ----------
  if (w < 4) {
    const int zrow = w*16 + l15;
    f32x4 pacc = z4;
    #pragma unroll
    for (int ks = 0; ks < 4; ++ks) {
      short8_t fq = *(const short8_t*)(smb + FCQ_B + zrow*256 +
                     ((ks*64 + l4*16) ^ ((zrow & 7) << 4)));
      pacc = __builtin_amdgcn_mfma_f32_16x16x32_bf16(fq, fq, pacc, 0, 0, 0);
    }
    float p0[4], m[4], e[4], s[4];
    #pragma unroll
    for (int reg = 0; reg < 4; ++reg) p0[reg] = pacc[reg] * inv_sqrt_dl;
    #pragma unroll
    for (int reg = 0; reg < 4; ++reg) {
      m[reg] = p0[reg];
      m[reg] = fmaxf(m[reg], __shfl_xor(m[reg], 1));
      m[reg] = fmaxf(m[reg], __shfl_xor(m[reg], 2));
      m[reg] = fmaxf(m[reg], __shfl_xor(m[reg], 4));
      m[reg] = fmaxf(m[reg], __shfl_xor(m[reg], 8));
      e[reg] = __expf(p0[reg] - m[reg]);
      s[reg] = e[reg];
      s[reg] += __shfl_xor(s[reg], 1);
      s[reg] += __shfl_xor(s[reg], 2);
      s[reg] += __shfl_xor(s[reg], 4);
      s[reg] += __shfl_xor(s[reg], 8);
    }
    #pragma unroll
    for (int reg = 0; reg < 4; ++reg)
      sAc[(w*16 + l4*4 + reg)*17 + l15] = e[reg] / s[reg];
  }
  __syncthreads();

  // ---------------- up GEMM prologue: issue Wu ch0 loads -------------------
  const int su_d = t >> 4;              // 0..31 (rows su_d, su_d+32)
  const int su_k8 = (t & 15) * 8;
  const int su_swz = (su_k8 * 2) ^ ((su_d & 7) << 4);
  int4 u0, u1;
  {
    const unsigned short* up = wub + su_k8;
    u0 = *(const int4*)(up + (size_t)su_d * DL_);
    u1 = *(const int4*)(up + (size_t)(su_d + 32) * DL_);
  }
  // ---------------- phase5: f_cc_hat = A_c @ f_c_hat (VALU) ----------------
  for (int p = t; p < ROWS*32; p += 512) {
    const int r = p >> 5, d4 = (p & 31)*4;
    const int g = r >> 4, z = r & 15;
    float ax = 0.f, ay = 0.f, az = 0.f, aw = 0.f;
    #pragma unroll
    for (int wq = 0; wq < 16; ++wq) {
      float a = sAc[(g*16+z)*17 + wq];
      const int fr = g*16 + wq;
      ushort4 fv = *(const ushort4*)(smb + SFCH_B + fr*256 + ((d4*2) ^ ((fr & 7) << 4)));
      ax += a*b2f((short)fv.x); ay += a*b2f((short)fv.y);
      az += a*b2f((short)fv.z); aw += a*b2f((short)fv.w);
    }
    ushort4 pk;
    pk.x = f2b(ax); pk.y = f2b(ay); pk.z = f2b(az); pk.w = f2b(aw);
    *(ushort4*)(smb + FCQ_B + r*256 + ((d4*2) ^ ((r & 7) << 4))) = pk;
  }
  // store-late Wu ch0 (region dead: KQ/ATB finished)
  *(int4*)(smb + WU0_B + su_d * 256 + su_swz) = u0;
  *(int4*)(smb + WU0_B + (su_d + 32) * 256 + su_swz) = u1;
  __syncthreads();

  // ---------------- up GEMM: double-buffered, 1 barrier/chunk --------------
  {
    char* cur_wu = smb + WU0_B; char* nxt_wu = smb + WU1_B;
    const int ad = (w & 3)*16 + l15;           // A row (d within chunk)
    const int aswz = (ad & 7) << 4;
    const int rbase = (w >> 2) * 32;           // two r-tiles per wave
    for (int ch = 0; ch < 8; ++ch) {
      if (ch < 7) {
        const unsigned short* up = wub + (size_t)(ch + 1)*64*DL_ + su_k8;
        u0 = *(const int4*)(up + (size_t)su_d * DL_);
        u1 = *(const int4*)(up + (size_t)(su_d + 32) * DL_);
      }
      f32x4 uacc[2]; uacc[0] = z4; uacc[1] = z4;
      #pragma unroll
      for (int ks = 0; ks < 4; ++ks) {
        short8_t afrag = *(const short8_t*)(cur_wu + ad*256 +
                          ((ks*64 + l4*16) ^ aswz));
        #pragma unroll
        for (int cf = 0; cf < 2; ++cf) {
          const int rr = rbase + cf*16 + l15;
          short8_t bfrag = *(const short8_t*)(smb + FCQ_B + rr*256 +
                            ((ks*64 + l4*16) ^ ((rr & 7) << 4)));
          uacc[cf] = __builtin_amdgcn_mfma_f32_16x16x32_bf16(afrag, bfrag, uacc[cf], 0, 0, 0);
        }
      }
      {
        const int d0 = ch*64 + (w & 3)*16 + l4*4;
        float4 bias = *(const float4*)(bc_up + d0);
        float4 fs4 = *(const float4*)(f_s + (size_t)b*D_ + d0);
        #pragma unroll
        for (int cf = 0; cf < 2; ++cf) {
          const int grow = row0 + rbase + cf*16 + l15;
          const size_t obase = (size_t)grow * D_;
          float4 fm4 = *(const float4*)(f_m + ((size_t)(grow >> 4))*D_ + d0);
          float4 fc4 = *(const float4*)(f_c + obase + d0);
          float4 o;
          o.x = uacc[cf][0] + bias.x + fc4.x + fm4.x/(1.f + __expf(-fm4.x*fs4.x));
          o.y = uacc[cf][1] + bias.y + fc4.y + fm4.y/(1.f + __expf(-fm4.y*fs4.y));
          o.z = uacc[cf][2] + bias.z + fc4.z + fm4.z/(1.f + __expf(-fm4.z*fs4.z));
          o.w = uacc[cf][3] + bias.w + fc4.w + fm4.w/(1.f + __expf(-fm4.w*fs4.w));
          *(float4*)(out + obase + d0) = o;
        }
      }
      if (ch < 7) {
        *(int4*)(nxt_wu + su_d * 256 + su_swz) = u0;
        *(int4*)(nxt_wu + (su_d + 32) * 256 + su_swz) = u1;
      }
      __syncthreads();
      char* tu = cur_wu; cur_wu = nxt_wu; nxt_wu = tu;
    }
  }
}

extern "C" void kernel_launch(void* const* d_in, const int* in_sizes, int n_in,
                              void* d_out, int out_size, void* d_ws, size_t ws_size,
                              hipStream_t stream) {
  (void)in_sizes; (void)n_in; (void)out_size; (void)ws_size;
  const float* f_c     = (const float*)d_in[0];
  const float* f_w     = (const float*)d_in[1];
  const float* f_s     = (const float*)d_in[2];
  const float* f_m     = (const float*)d_in[3];
  const float* Wc_down = (const float*)d_in[4];
  const float* bc_down = (const float*)d_in[5];
  const float* Ww      = (const float*)d_in[6];
  const float* bw      = (const float*)d_in[7];
  const float* Ws      = (const float*)d_in[8];
  const float* bs      = (const float*)d_in[9];
  const float* Wq      = (const float*)d_in[10];
  const float* bq      = (const float*)d_in[11];
  const float* Wk      = (const float*)d_in[12];
  const float* bk      = (const float*)d_in[13];
  const float* Wc_up   = (const float*)d_in[14];
  const float* bc_up   = (const float*)d_in[15];
  float* out = (float*)d_out;
  float* wsf = (float*)d_ws;
  unsigned short* wdb = (unsigned short*)(wsf + WS_WDB);
  unsigned short* wub = (unsigned short*)(wsf + WS_WUB);

  hipLaunchKernelGGL(k0_convert, dim3(128), dim3(256), 0, stream,
                     Wc_down, Wc_up, wdb, wub);
  hipLaunchKernelGGL(k1_small, dim3(B_*L_), dim3(128), 0, stream,
                     f_w, f_s, Ww, bw, Ws, bs, Wq, bq, Wk, bk, wsf);
  hipLaunchKernelGGL(k2_fused, dim3(M_/ROWS), dim3(512), 0, stream,
                     f_c, wdb, wub, bc_down, bc_up, f_m, f_s, wsf, out);
}